// Round 2
// baseline (694.593 us; speedup 1.0000x reference)
//
#include <hip/hip_runtime.h>

#define DGRID 128
#define E1 127
#define E2 125
#define E3 123

// x2 tile per block
#define TZ 4
#define TY 8
#define TX 8
// x1 tile = (TZ+2)x(TY+2)x(TX+2)
#define X1Z (TZ + 2)
#define X1Y (TY + 2)
#define X1X (TX + 2)
#define NX1 (X1Z * X1Y * X1X)          // 600
// dense tile = (TZ+3)x(TY+3)x(TX+3)
#define DZ (TZ + 3)
#define DY (TY + 3)
#define DX (TX + 3)
#define NDENSE (DZ * DY * DX * 3)      // 2541

// ---------------- stage 0: zero dense grid ----------------
__global__ __launch_bounds__(256) void zero_k(float4* __restrict__ p, int n4) {
    int i = blockIdx.x * 256 + threadIdx.x;
    if (i < n4) p[i] = make_float4(0.f, 0.f, 0.f, 0.f);
}

// ---------------- stage 1: scatter voxels into dense grid ----------------
__global__ __launch_bounds__(256) void scatter_k(const int* __restrict__ coords,
                                                 const float* __restrict__ voxels,
                                                 float* __restrict__ dense, int N) {
    int i = blockIdx.x * blockDim.x + threadIdx.x;
    if (i >= N * 3) return;
    int n = i / 3, c = i - n * 3;
    int b = coords[n * 4 + 0];
    int z = coords[n * 4 + 1];
    int y = coords[n * 4 + 2];
    int x = coords[n * 4 + 3];
    int idx = (((b * DGRID + z) * DGRID + y) * DGRID + x) * 3 + c;
    atomicAdd(&dense[idx], voxels[n * 3 + c]);
}

// ---------------- stage 2: fused conv1+conv2  dense -> x2 [B,125,125,125,5] ----------------
__global__ __launch_bounds__(256) void conv12_k(const float* __restrict__ dense,
                                                const float* __restrict__ W1,
                                                const float* __restrict__ W2,
                                                float* __restrict__ x2) {
    __shared__ float sW1[216];
    __shared__ float sW2[1215];
    __shared__ float sD[NDENSE];       // [DZ][DY][DX][3]
    __shared__ float sX1[NX1 * 9];     // [X1Z][X1Y][X1X][9]

    const int tid = threadIdx.x;
    for (int i = tid; i < 216; i += 256) sW1[i] = W1[i];
    for (int i = tid; i < 1215; i += 256) sW2[i] = W2[i];

    // decompose block -> (b, tz, ty, tx); 32 z-tiles, 16 y, 16 x per batch
    int blk = blockIdx.x;
    int txt = blk & 15; blk >>= 4;
    int tyt = blk & 15; blk >>= 4;
    int tzt = blk & 31; blk >>= 5;
    int b = blk;
    const int z0 = tzt * TZ, y0 = tyt * TY, x0 = txt * TX;

    // ---- load dense tile (clamped at grid edge; clamped values only feed invalid outputs)
    for (int i = tid; i < NDENSE; i += 256) {
        int c = i % 3; int t = i / 3;
        int dx = t % DX; t /= DX;
        int dy = t % DY; int dz = t / DY;
        int gz = min(z0 + dz, DGRID - 1);
        int gy = min(y0 + dy, DGRID - 1);
        int gx = min(x0 + dx, DGRID - 1);
        sD[i] = dense[(size_t)(((b * DGRID + gz) * DGRID + gy) * DGRID + gx) * 3 + c];
    }
    __syncthreads();

    // ---- compute x1 tile in LDS (conv1: 2x2x2x3 -> 9)
    for (int p = tid; p < NX1; p += 256) {
        int xx = p % X1X; int t = p / X1X;
        int xy = t % X1Y; int xz = t / X1Y;
        float acc[9];
#pragma unroll
        for (int o = 0; o < 9; ++o) acc[o] = 0.f;
#pragma unroll
        for (int kz = 0; kz < 2; ++kz)
#pragma unroll
            for (int ky = 0; ky < 2; ++ky)
#pragma unroll
                for (int kx = 0; kx < 2; ++kx) {
                    const float* dp = sD + (((xz + kz) * DY + (xy + ky)) * DX + (xx + kx)) * 3;
                    const float* wp = sW1 + ((kz * 2 + ky) * 2 + kx) * 27;
#pragma unroll
                    for (int ci = 0; ci < 3; ++ci) {
                        float v = dp[ci];
#pragma unroll
                        for (int o = 0; o < 9; ++o) acc[o] += v * wp[ci * 9 + o];
                    }
                }
        float* op = sX1 + p * 9;
#pragma unroll
        for (int o = 0; o < 9; ++o) op[o] = acc[o];
    }
    __syncthreads();

    // ---- conv2 from LDS (3x3x3x9 -> 5), one output per thread
    int lx = tid & 7; int lt = tid >> 3;
    int ly = lt & 7;  int lz = lt >> 3;
    int z = z0 + lz, y = y0 + ly, x = x0 + lx;
    if (z >= E2 || y >= E2 || x >= E2) return;

    float acc[5];
#pragma unroll
    for (int o = 0; o < 5; ++o) acc[o] = 0.f;
#pragma unroll
    for (int kz = 0; kz < 3; ++kz)
#pragma unroll
        for (int ky = 0; ky < 3; ++ky)
#pragma unroll
            for (int kx = 0; kx < 3; ++kx) {
                const float* p = sX1 + (((lz + kz) * X1Y + (ly + ky)) * X1X + (lx + kx)) * 9;
                const float* wp = sW2 + ((kz * 3 + ky) * 3 + kx) * 45;
#pragma unroll
                for (int ci = 0; ci < 9; ++ci) {
                    float v = p[ci];
#pragma unroll
                    for (int o = 0; o < 5; ++o) acc[o] += v * wp[ci * 5 + o];
                }
            }
    float* op = x2 + (size_t)(((b * E2 + z) * E2 + y) * E2 + x) * 5;
#pragma unroll
    for (int o = 0; o < 5; ++o) op[o] = acc[o];
}

// ---------------- stage 3: conv3 + bias + relu  [B,125,125,125,5] -> [B,123,123,123,3] ----------------
__global__ __launch_bounds__(256) void conv3_k(const float* __restrict__ x2,
                                               const float* __restrict__ W3,
                                               const float* __restrict__ b3,
                                               float* __restrict__ out) {
    __shared__ float w[405];
    __shared__ float bias[3];
    for (int i = threadIdx.x; i < 405; i += 256) w[i] = W3[i];
    if (threadIdx.x < 3) bias[threadIdx.x] = b3[threadIdx.x];
    __syncthreads();
    int pos = blockIdx.x * 256 + threadIdx.x;
    const int tot = 2 * E3 * E3 * E3;
    if (pos >= tot) return;
    int x = pos % E3; int t = pos / E3;
    int y = t % E3;   t /= E3;
    int z = t % E3;   int b = t / E3;

    float acc[3];
#pragma unroll
    for (int o = 0; o < 3; ++o) acc[o] = bias[o];

    for (int kz = 0; kz < 3; ++kz)
        for (int ky = 0; ky < 3; ++ky)
#pragma unroll
            for (int kx = 0; kx < 3; ++kx) {
                const float* p = x2 +
                    (size_t)((((b * E2) + z + kz) * E2 + (y + ky)) * E2 + (x + kx)) * 5;
                const float* wp = w + ((kz * 3 + ky) * 3 + kx) * 15;
#pragma unroll
                for (int ci = 0; ci < 5; ++ci) {
                    float v = p[ci];
#pragma unroll
                    for (int o = 0; o < 3; ++o) acc[o] += v * wp[ci * 3 + o];
                }
            }
    float* op = out + (size_t)pos * 3;
#pragma unroll
    for (int o = 0; o < 3; ++o) op[o] = fmaxf(acc[o], 0.f);
}

extern "C" void kernel_launch(void* const* d_in, const int* in_sizes, int n_in,
                              void* d_out, int out_size, void* d_ws, size_t ws_size,
                              hipStream_t stream) {
    const int*   coords = (const int*)d_in[0];
    const float* voxels = (const float*)d_in[1];
    const float* W1     = (const float*)d_in[2];
    const float* W2     = (const float*)d_in[3];
    const float* W3     = (const float*)d_in[4];
    const float* b3     = (const float*)d_in[5];
    float* out = (float*)d_out;

    const int N = in_sizes[0] / 4;  // 100000

    // workspace layout: dense (50.3 MB) + x2 (78.1 MB) = 128.5 MB
    char* ws = (char*)d_ws;
    const size_t dense_elems = (size_t)2 * DGRID * DGRID * DGRID * 3;   // 12,582,912
    const size_t dense_bytes = dense_elems * sizeof(float);
    float* dense = (float*)ws;
    float* x2    = (float*)(ws + dense_bytes);

    // stage 0: zero dense (kernel, not memset, to stay graph-capture-safe)
    const int n4 = (int)(dense_elems / 4);
    zero_k<<<(n4 + 255) / 256, 256, 0, stream>>>((float4*)dense, n4);

    // stage 1: scatter
    scatter_k<<<(N * 3 + 255) / 256, 256, 0, stream>>>(coords, voxels, dense, N);

    // stage 2: fused conv1+conv2
    const int nblk12 = 2 * 32 * 16 * 16;  // b * ceil(125/4) * ceil(125/8) * ceil(125/8)
    conv12_k<<<nblk12, 256, 0, stream>>>(dense, W1, W2, x2);

    // stage 3: conv3 + bias + relu
    const int tot3 = 2 * E3 * E3 * E3;
    conv3_k<<<(tot3 + 255) / 256, 256, 0, stream>>>(x2, W3, b3, out);
}